// Round 1
// baseline (482.099 us; speedup 1.0000x reference)
//
#include <hip/hip_runtime.h>
#include <hip/hip_bf16.h>

typedef unsigned short u16;
typedef short s16x8 __attribute__((ext_vector_type(8)));
typedef float f32x4 __attribute__((ext_vector_type(4)));

#define LOG2E 1.44269504088896f

__device__ __forceinline__ u16 f2b(float f){
    __hip_bfloat16 h = __float2bfloat16(f);
    return __builtin_bit_cast(unsigned short, h);
}
__device__ __forceinline__ float b2f(u16 u){
    __hip_bfloat16 h = __builtin_bit_cast(__hip_bfloat16, u);
    return __bfloat162float(h);
}

// ---------------- elementwise fp32 -> bf16 ----------------
__global__ void k_f32_to_bf16(const float* __restrict__ in, u16* __restrict__ out, int n){
    int i = blockIdx.x*blockDim.x + threadIdx.x;
    int stride = gridDim.x*blockDim.x;
    for (; i < n; i += stride) out[i] = f2b(in[i]);
}

// ---------------- W (KxN fp32) -> Wt (NxK bf16) ----------------
__global__ void k_transpose_bf16(const float* __restrict__ W, u16* __restrict__ Wt, int K, int N){
    __shared__ float tile[32][33];
    int n0 = blockIdx.x*32, k0 = blockIdx.y*32;
    int c = threadIdx.x & 31, r0 = threadIdx.x >> 5;
#pragma unroll
    for (int it = 0; it < 4; ++it){
        int r = r0 + it*8;
        tile[r][c] = W[(size_t)(k0+r)*N + n0 + c];
    }
    __syncthreads();
#pragma unroll
    for (int it = 0; it < 4; ++it){
        int r = r0 + it*8;
        Wt[(size_t)(n0+r)*K + k0 + c] = f2b(tile[c][r]);
    }
}

// ---------------- Vb[(b,h,t,d)] = bf16(x[b,t,h*64+d]) ----------------
__global__ void k_build_v(const float* __restrict__ x, u16* __restrict__ Vb){
    int i = blockIdx.x*blockDim.x + threadIdx.x;
    int stride = gridDim.x*blockDim.x;
    for (; i < (1<<22); i += stride){
        int dd = i & 63;
        int t  = (i >> 6) & 2047;
        int h  = (i >> 17) & 15;
        int b  = i >> 21;
        Vb[i] = f2b(x[((size_t)(b*2048 + t))*1024 + h*64 + dd]);
    }
}

// ---------------- bf16 MFMA GEMM, 128x128 tile, BK=64 ----------------
// A: MxK row-major bf16. Bt: NxK row-major bf16 (pre-transposed weights).
// MODE 0: out0=Qb (bf16, scaled 0.125, BHTd), out1=Kb (bf16, BHTd), bias=b_attn
// MODE 1: out0=K2b (bf16, BHTd), bias=b_k2
// MODE 2: outF=d_out fp32 row-major, val + 2*b_proj
template<int MODE>
__global__ __launch_bounds__(256) void k_gemm(const u16* __restrict__ A, const u16* __restrict__ Bt,
                       const float* __restrict__ bias, float* __restrict__ outF,
                       u16* __restrict__ out0, u16* __restrict__ out1,
                       int M, int N, int K){
    __shared__ u16 As[128][72];
    __shared__ u16 Bs[128][72];
    int m0 = blockIdx.y * 128, n0 = blockIdx.x * 128;
    int tid = threadIdx.x;
    int lane = tid & 63, w = tid >> 6;
    int wm = w >> 1, wn = w & 1;
    int l15 = lane & 15, l4 = lane >> 4;
    f32x4 acc[4][4] = {};

    for (int kt = 0; kt < K; kt += 64){
#pragma unroll
        for (int it = 0; it < 4; ++it){
            int c = tid + 256*it;
            int row = c >> 3, seg = c & 7;
            *(uint4*)&As[row][seg*8] = *(const uint4*)&A[(size_t)(m0+row)*K + kt + seg*8];
            *(uint4*)&Bs[row][seg*8] = *(const uint4*)&Bt[(size_t)(n0+row)*K + kt + seg*8];
        }
        __syncthreads();
#pragma unroll
        for (int kk = 0; kk < 2; ++kk){
            s16x8 a[4], b[4];
#pragma unroll
            for (int mi = 0; mi < 4; ++mi)
                a[mi] = *(const s16x8*)&As[wm*64 + mi*16 + l15][kk*32 + l4*8];
#pragma unroll
            for (int ni = 0; ni < 4; ++ni)
                b[ni] = *(const s16x8*)&Bs[wn*64 + ni*16 + l15][kk*32 + l4*8];
#pragma unroll
            for (int mi = 0; mi < 4; ++mi)
#pragma unroll
                for (int ni = 0; ni < 4; ++ni)
                    acc[mi][ni] = __builtin_amdgcn_mfma_f32_16x16x32_bf16(a[mi], b[ni], acc[mi][ni], 0,0,0);
        }
        __syncthreads();
    }

#pragma unroll
    for (int mi = 0; mi < 4; ++mi){
        int growb = m0 + wm*64 + mi*16 + l4*4;
#pragma unroll
        for (int ni = 0; ni < 4; ++ni){
            int gcol = n0 + wn*64 + ni*16 + l15;
            float bv = bias[gcol];
#pragma unroll
            for (int r = 0; r < 4; ++r){
                int row = growb + r;
                float val = acc[mi][ni][r];
                if (MODE == 2){
                    outF[(size_t)row*N + gcol] = val + 2.0f*bv;
                } else {
                    val += bv;
                    int bb = row >> 11, t = row & 2047;
                    if (MODE == 0){
                        if (gcol < 1024){
                            int h = gcol >> 6, dd = gcol & 63;
                            out0[(((size_t)(bb*16+h))*2048 + t)*64 + dd] = f2b(val*0.125f);
                        } else {
                            int c2 = gcol - 1024;
                            int h = c2 >> 6, dd = c2 & 63;
                            out1[(((size_t)(bb*16+h))*2048 + t)*64 + dd] = f2b(val);
                        }
                    } else {
                        int h = gcol >> 6, dd = gcol & 63;
                        out0[(((size_t)(bb*16+h))*2048 + t)*64 + dd] = f2b(val);
                    }
                }
            }
        }
    }
}

// ---------------- flash attention (causal), 64 q-rows/block, 4 waves ----------------
// Q,K,V bf16 in (bh, row, 64) with per-matrix row strides; O fp32 (bh, row, 64).
__global__ __launch_bounds__(256) void k_flash(const u16* __restrict__ Q, const u16* __restrict__ Km,
                        const u16* __restrict__ V, float* __restrict__ O,
                        int Tq, int Tkv, int qstride, int kstride, int vstride, int ostride, int qoff){
    __shared__ u16 Ks[64][72];
    __shared__ u16 VTs[64][72];
    __shared__ u16 Ps[64][72];
    int bh = blockIdx.y;
    int qs = blockIdx.x * 64;
    if (qs >= Tq) return;
    int tid = threadIdx.x, lane = tid & 63, w = tid >> 6;
    int l15 = lane & 15, l4 = lane >> 4;
    const u16* Qp = Q + ((size_t)bh*qstride + qoff)*64;
    const u16* Kp = Km + (size_t)bh*kstride*64;
    const u16* Vp = V + (size_t)bh*vstride*64;

    s16x8 aq[2];
    {
        int qrow = qs + w*16 + l15; if (qrow > Tq-1) qrow = Tq-1;
#pragma unroll
        for (int kk = 0; kk < 2; ++kk)
            aq[kk] = *(const s16x8*)&Qp[(size_t)qrow*64 + kk*32 + l4*8];
    }
    f32x4 Of[4] = {};
    float m_r[4], l_r[4];
#pragma unroll
    for (int r=0;r<4;++r){ m_r[r] = -INFINITY; l_r[r] = 0.f; }

    int nt = (qs >> 6) + 1;
    for (int ti = 0; ti < nt; ++ti){
        int ks0 = ti*64;
        {   // stage K row-major and V transposed
            int row = tid >> 2, q4 = tid & 3;
            int srow = ks0 + row; if (srow > Tkv-1) srow = Tkv-1;
            *(uint4*)&Ks[row][q4*16]     = *(const uint4*)&Kp[(size_t)srow*64 + q4*16];
            *(uint4*)&Ks[row][q4*16 + 8] = *(const uint4*)&Kp[(size_t)srow*64 + q4*16 + 8];
            u16 tmp[16];
            *(uint4*)&tmp[0] = *(const uint4*)&Vp[(size_t)srow*64 + q4*16];
            *(uint4*)&tmp[8] = *(const uint4*)&Vp[(size_t)srow*64 + q4*16 + 8];
#pragma unroll
            for (int j = 0; j < 16; ++j) VTs[q4*16 + j][row] = tmp[j];
        }
        __syncthreads();
        // S = Q K^T
        f32x4 sf[4] = {};
#pragma unroll
        for (int kk = 0; kk < 2; ++kk)
#pragma unroll
            for (int ni = 0; ni < 4; ++ni){
                s16x8 bk = *(const s16x8*)&Ks[ni*16 + l15][kk*32 + l4*8];
                sf[ni] = __builtin_amdgcn_mfma_f32_16x16x32_bf16(aq[kk], bk, sf[ni], 0,0,0);
            }
        // mask + online softmax (rows: l4*4+r, cols: ni*16+l15)
#pragma unroll
        for (int r = 0; r < 4; ++r){
            int grow = qs + w*16 + l4*4 + r;
            float mx = -INFINITY;
#pragma unroll
            for (int ni = 0; ni < 4; ++ni){
                int col = ks0 + ni*16 + l15;
                float s = sf[ni][r];
                if (col > grow || col >= Tkv) s = -INFINITY;
                sf[ni][r] = s;
                mx = fmaxf(mx, s);
            }
            mx = fmaxf(mx, __shfl_xor(mx, 1));
            mx = fmaxf(mx, __shfl_xor(mx, 2));
            mx = fmaxf(mx, __shfl_xor(mx, 4));
            mx = fmaxf(mx, __shfl_xor(mx, 8));
            float mnew = fmaxf(m_r[r], mx);
            float scale = exp2f((m_r[r] - mnew)*LOG2E);
            float rs = 0.f;
#pragma unroll
            for (int ni = 0; ni < 4; ++ni){
                float p = exp2f((sf[ni][r] - mnew)*LOG2E);
                u16 pb = f2b(p);
                rs += b2f(pb);
                Ps[w*16 + l4*4 + r][ni*16 + l15] = pb;
            }
            rs += __shfl_xor(rs, 1);
            rs += __shfl_xor(rs, 2);
            rs += __shfl_xor(rs, 4);
            rs += __shfl_xor(rs, 8);
            l_r[r] = l_r[r]*scale + rs;
            m_r[r] = mnew;
#pragma unroll
            for (int di = 0; di < 4; ++di) Of[di][r] *= scale;
        }
        __syncthreads();
        // O += P V
#pragma unroll
        for (int kk = 0; kk < 2; ++kk){
            s16x8 ap = *(const s16x8*)&Ps[w*16 + l15][kk*32 + l4*8];
#pragma unroll
            for (int di = 0; di < 4; ++di){
                s16x8 bv = *(const s16x8*)&VTs[di*16 + l15][kk*32 + l4*8];
                Of[di] = __builtin_amdgcn_mfma_f32_16x16x32_bf16(ap, bv, Of[di], 0,0,0);
            }
        }
        __syncthreads();
    }
#pragma unroll
    for (int r = 0; r < 4; ++r){
        int grow = qs + w*16 + l4*4 + r;
        if (grow < Tq){
            float inv = 1.0f / l_r[r];
#pragma unroll
            for (int di = 0; di < 4; ++di)
                O[((size_t)bh*ostride + grow)*64 + di*16 + l15] = Of[di][r] * inv;
        }
    }
}

// ---------------- e[bh, j, d] = v[bh, j+1, d] - y[bh, j, d]  (j in 0..2046) ----------------
__global__ void k_compute_e(const float* __restrict__ x, const float* __restrict__ y1,
                            u16* __restrict__ Eb){
    int i = blockIdx.x*blockDim.x + threadIdx.x;
    int stride = gridDim.x*blockDim.x;
    const int NTOT = 32*2047*64;
    for (; i < NTOT; i += stride){
        int dd = i & 63;
        int rem = i >> 6;
        int j = rem % 2047;
        int bh = rem / 2047;
        int b = bh >> 4, h = bh & 15;
        float v = x[((size_t)(b*2048 + (j+1)))*1024 + h*64 + dd];
        float yv = y1[((size_t)bh*2048 + j)*64 + dd];
        Eb[i] = f2b(v - yv);
    }
}

// ---------------- ysum (B,T,C) bf16 = y1 + shift(y2) ----------------
__global__ void k_ysum(const float* __restrict__ y1, const float* __restrict__ y2,
                       u16* __restrict__ ys){
    int i = blockIdx.x*blockDim.x + threadIdx.x;
    int stride = gridDim.x*blockDim.x;
    for (; i < (1<<22); i += stride){
        int c = i & 1023;
        int t = (i >> 10) & 2047;
        int b = i >> 21;
        int h = c >> 6, dd = c & 63;
        int bh = b*16 + h;
        float s = y1[((size_t)bh*2048 + t)*64 + dd];
        if (t > 0) s += y2[((size_t)bh*2047 + (t-1))*64 + dd];
        ys[i] = f2b(s);
    }
}

extern "C" void kernel_launch(void* const* d_in, const int* in_sizes, int n_in,
                              void* d_out, int out_size, void* d_ws, size_t ws_size,
                              hipStream_t stream){
    const float* x      = (const float*)d_in[0];
    const float* W_attn = (const float*)d_in[1];
    const float* b_attn = (const float*)d_in[2];
    const float* W_k2   = (const float*)d_in[3];
    const float* b_k2   = (const float*)d_in[4];
    const float* W_proj = (const float*)d_in[5];
    const float* b_proj = (const float*)d_in[6];
    float* out = (float*)d_out;

    char* ws = (char*)d_ws;
    size_t off = 0;
    auto alloc = [&](size_t bytes)->void*{
        void* p = ws + off; off += (bytes + 255) & ~size_t(255); return p;
    };
    u16* xb   = (u16*)alloc((size_t)4096*1024*2);
    u16* WaT  = (u16*)alloc((size_t)2048*1024*2);
    u16* Wk2T = (u16*)alloc((size_t)1024*1024*2);
    u16* WpT  = (u16*)alloc((size_t)1024*1024*2);
    u16* Qb   = (u16*)alloc((size_t)32*2048*64*2);
    u16* Kb   = (u16*)alloc((size_t)32*2048*64*2);
    u16* Vb   = (u16*)alloc((size_t)32*2048*64*2);
    u16* K2b  = (u16*)alloc((size_t)32*2048*64*2);
    u16* Eb   = (u16*)alloc((size_t)32*2047*64*2);
    float* y1 = (float*)alloc((size_t)32*2048*64*4);
    float* y2 = (float*)alloc((size_t)32*2047*64*4);
    u16* ys   = (u16*)alloc((size_t)4096*1024*2);

    k_f32_to_bf16<<<2048, 256, 0, stream>>>(x, xb, 4096*1024);
    k_transpose_bf16<<<dim3(64, 32), 256, 0, stream>>>(W_attn, WaT, 1024, 2048);
    k_transpose_bf16<<<dim3(32, 32), 256, 0, stream>>>(W_k2, Wk2T, 1024, 1024);
    k_transpose_bf16<<<dim3(32, 32), 256, 0, stream>>>(W_proj, WpT, 1024, 1024);
    k_build_v<<<2048, 256, 0, stream>>>(x, Vb);

    k_gemm<0><<<dim3(16, 32), 256, 0, stream>>>(xb, WaT, b_attn, nullptr, Qb, Kb, 4096, 2048, 1024);
    k_gemm<1><<<dim3(8, 32), 256, 0, stream>>>(xb, Wk2T, b_k2, nullptr, K2b, nullptr, 4096, 1024, 1024);

    k_flash<<<dim3(32, 32), 256, 0, stream>>>(Qb, Kb, Vb, y1, 2048, 2048, 2048, 2048, 2048, 2048, 0);
    k_compute_e<<<2048, 256, 0, stream>>>(x, y1, Eb);
    k_flash<<<dim3(32, 32), 256, 0, stream>>>(Qb, K2b, Eb, y2, 2047, 2047, 2048, 2048, 2047, 2047, 1);
    k_ysum<<<2048, 256, 0, stream>>>(y1, y2, ys);

    k_gemm<2><<<dim3(8, 32), 256, 0, stream>>>(ys, WpT, b_proj, out, nullptr, nullptr, 4096, 1024, 1024);
}

// Round 3
// 393.013 us; speedup vs baseline: 1.2267x; 1.2267x over previous
//
#include <hip/hip_runtime.h>
#include <hip/hip_bf16.h>

typedef unsigned short u16;
typedef short s16x8 __attribute__((ext_vector_type(8)));
typedef float f32x4 __attribute__((ext_vector_type(4)));

#define LOG2E 1.44269504088896f

__device__ __forceinline__ u16 f2b(float f){
    __hip_bfloat16 h = __float2bfloat16(f);
    return __builtin_bit_cast(unsigned short, h);
}
__device__ __forceinline__ float b2f(u16 u){
    __hip_bfloat16 h = __builtin_bit_cast(__hip_bfloat16, u);
    return __bfloat162float(h);
}
__device__ __forceinline__ unsigned int pk2(float a, float b){
    return (unsigned int)f2b(a) | ((unsigned int)f2b(b) << 16);
}

// ---------------- elementwise fp32 -> bf16 (vectorized float4 -> 4x bf16) ----------------
__global__ void k_f32_to_bf16(const float* __restrict__ in, u16* __restrict__ out, int n4){
    int i = blockIdx.x*blockDim.x + threadIdx.x;
    int stride = gridDim.x*blockDim.x;
    for (; i < n4; i += stride){
        float4 a = *(const float4*)&in[(size_t)i*4];
        uint2 o;
        o.x = pk2(a.x, a.y);
        o.y = pk2(a.z, a.w);
        *(uint2*)&out[(size_t)i*4] = o;
    }
}

// ---------------- W (KxN fp32) -> Wt (NxK bf16) ----------------
__global__ void k_transpose_bf16(const float* __restrict__ W, u16* __restrict__ Wt, int K, int N){
    __shared__ float tile[32][33];
    int n0 = blockIdx.x*32, k0 = blockIdx.y*32;
    int c = threadIdx.x & 31, r0 = threadIdx.x >> 5;
#pragma unroll
    for (int it = 0; it < 4; ++it){
        int r = r0 + it*8;
        tile[r][c] = W[(size_t)(k0+r)*N + n0 + c];
    }
    __syncthreads();
#pragma unroll
    for (int it = 0; it < 4; ++it){
        int r = r0 + it*8;
        Wt[(size_t)(n0+r)*K + k0 + c] = f2b(tile[c][r]);
    }
}

// ---------------- VT[(b,h,d,t)] = bf16(x[b,t,h*64+d]) : transposed in global ----------------
__global__ __launch_bounds__(256) void k_build_vT(const float* __restrict__ x, u16* __restrict__ VT){
    __shared__ float tile[64][65];
    int bh = blockIdx.x, t0 = blockIdx.y*64;
    int b = bh >> 4, h = bh & 15;
    int tid = threadIdx.x;
    {
        int tt = tid >> 2, ds = (tid & 3)*16;
        const float* xp = &x[((size_t)(b*2048) + t0 + tt)*1024 + h*64 + ds];
#pragma unroll
        for (int j4 = 0; j4 < 4; ++j4){
            float4 a = *(const float4*)&xp[j4*4];
            tile[tt][ds + j4*4 + 0] = a.x;
            tile[tt][ds + j4*4 + 1] = a.y;
            tile[tt][ds + j4*4 + 2] = a.z;
            tile[tt][ds + j4*4 + 3] = a.w;
        }
    }
    __syncthreads();
    {
        int dd = tid >> 2, ts = (tid & 3)*16;
        unsigned int o[8];
#pragma unroll
        for (int j = 0; j < 8; ++j)
            o[j] = pk2(tile[ts + 2*j][dd], tile[ts + 2*j + 1][dd]);
        u16* dst = &VT[((size_t)(bh*64 + dd))*2048 + t0 + ts];
        *(uint4*)&dst[0] = *(uint4*)&o[0];
        *(uint4*)&dst[8] = *(uint4*)&o[4];
    }
}

// ---------------- ET[(bh,d,j)] = bf16(x[b,j+1,h*64+d] - y1[bh,j,d]), j<=2046, stride 2048 ----------------
__global__ __launch_bounds__(256) void k_compute_eT(const float* __restrict__ x, const float* __restrict__ y1,
                                                    u16* __restrict__ ET){
    __shared__ float tile[64][65];
    int bh = blockIdx.x, j0 = blockIdx.y*64;
    int b = bh >> 4, h = bh & 15;
    int tid = threadIdx.x;
    {
        int tt = tid >> 2, ds = (tid & 3)*16;
        int j = j0 + tt; if (j > 2046) j = 2046;
        const float* xp = &x[((size_t)(b*2048) + j + 1)*1024 + h*64 + ds];
        const float* yp = &y1[((size_t)bh*2048 + j)*64 + ds];
#pragma unroll
        for (int j4 = 0; j4 < 4; ++j4){
            float4 a = *(const float4*)&xp[j4*4];
            float4 c = *(const float4*)&yp[j4*4];
            tile[tt][ds + j4*4 + 0] = a.x - c.x;
            tile[tt][ds + j4*4 + 1] = a.y - c.y;
            tile[tt][ds + j4*4 + 2] = a.z - c.z;
            tile[tt][ds + j4*4 + 3] = a.w - c.w;
        }
    }
    __syncthreads();
    {
        int dd = tid >> 2, ts = (tid & 3)*16;
        unsigned int o[8];
#pragma unroll
        for (int j = 0; j < 8; ++j)
            o[j] = pk2(tile[ts + 2*j][dd], tile[ts + 2*j + 1][dd]);
        u16* dst = &ET[((size_t)(bh*64 + dd))*2048 + j0 + ts];
        *(uint4*)&dst[0] = *(uint4*)&o[0];
        *(uint4*)&dst[8] = *(uint4*)&o[4];
    }
}

// ---------------- bf16 MFMA GEMM, 128x128 tile, BK=64 ----------------
template<int MODE>
__global__ __launch_bounds__(256) void k_gemm(const u16* __restrict__ A, const u16* __restrict__ Bt,
                       const float* __restrict__ bias, float* __restrict__ outF,
                       u16* __restrict__ out0, u16* __restrict__ out1,
                       int M, int N, int K){
    __shared__ u16 As[128][72];
    __shared__ u16 Bs[128][72];
    int m0 = blockIdx.y * 128, n0 = blockIdx.x * 128;
    int tid = threadIdx.x;
    int lane = tid & 63, w = tid >> 6;
    int wm = w >> 1, wn = w & 1;
    int l15 = lane & 15, l4 = lane >> 4;
    f32x4 acc[4][4] = {};

    for (int kt = 0; kt < K; kt += 64){
#pragma unroll
        for (int it = 0; it < 4; ++it){
            int c = tid + 256*it;
            int row = c >> 3, seg = c & 7;
            *(uint4*)&As[row][seg*8] = *(const uint4*)&A[(size_t)(m0+row)*K + kt + seg*8];
            *(uint4*)&Bs[row][seg*8] = *(const uint4*)&Bt[(size_t)(n0+row)*K + kt + seg*8];
        }
        __syncthreads();
#pragma unroll
        for (int kk = 0; kk < 2; ++kk){
            s16x8 a[4], b[4];
#pragma unroll
            for (int mi = 0; mi < 4; ++mi)
                a[mi] = *(const s16x8*)&As[wm*64 + mi*16 + l15][kk*32 + l4*8];
#pragma unroll
            for (int ni = 0; ni < 4; ++ni)
                b[ni] = *(const s16x8*)&Bs[wn*64 + ni*16 + l15][kk*32 + l4*8];
#pragma unroll
            for (int mi = 0; mi < 4; ++mi)
#pragma unroll
                for (int ni = 0; ni < 4; ++ni)
                    acc[mi][ni] = __builtin_amdgcn_mfma_f32_16x16x32_bf16(a[mi], b[ni], acc[mi][ni], 0,0,0);
        }
        __syncthreads();
    }

#pragma unroll
    for (int mi = 0; mi < 4; ++mi){
        int growb = m0 + wm*64 + mi*16 + l4*4;
#pragma unroll
        for (int ni = 0; ni < 4; ++ni){
            int gcol = n0 + wn*64 + ni*16 + l15;
            float bv = bias[gcol];
#pragma unroll
            for (int r = 0; r < 4; ++r){
                int row = growb + r;
                float val = acc[mi][ni][r];
                if (MODE == 2){
                    outF[(size_t)row*N + gcol] = val + 2.0f*bv;
                } else {
                    val += bv;
                    int bb = row >> 11, t = row & 2047;
                    if (MODE == 0){
                        if (gcol < 1024){
                            int h = gcol >> 6, dd = gcol & 63;
                            out0[(((size_t)(bb*16+h))*2048 + t)*64 + dd] = f2b(val*0.125f);
                        } else {
                            int c2 = gcol - 1024;
                            int h = c2 >> 6, dd = c2 & 63;
                            out1[(((size_t)(bb*16+h))*2048 + t)*64 + dd] = f2b(val);
                        }
                    } else {
                        int h = gcol >> 6, dd = gcol & 63;
                        out0[(((size_t)(bb*16+h))*2048 + t)*64 + dd] = f2b(val);
                    }
                }
            }
        }
    }
}

// ---------------- flash attention (causal), 64 q-rows/block, 4 waves ----------------
// Q,K bf16 rows (bh, t, 64); VT bf16 transposed (bh, d=64, t) with row length vtstride.
// O fp32 (bh, t, 64). Grid: x = bh (32), y enumerates q-tiles via swizzle.
__global__ __launch_bounds__(256) void k_flash(const u16* __restrict__ Q, const u16* __restrict__ Km,
                        const u16* __restrict__ VT, float* __restrict__ O,
                        int Tq, int Tkv, int qstride, int kstride, int vtstride, int ostride, int qoff){
    __shared__ u16 Ks[64][72];
    __shared__ u16 VTs[64][72];
    __shared__ u16 Ps[64][72];
    int bh = blockIdx.x;
    int qt = (int)((blockIdx.y + blockIdx.x) & 31);   // balance: each CU's blocks span qtiles
    int qs = qt * 64;
    int tid = threadIdx.x, lane = tid & 63, w = tid >> 6;
    int l15 = lane & 15, l4 = lane >> 4;
    const u16* Qp = Q + ((size_t)bh*qstride + qoff)*64;
    const u16* Kp = Km + (size_t)bh*kstride*64;
    const u16* Vp = VT + (size_t)bh*64*vtstride;

    s16x8 aq[2];
    {
        int qrow = qs + w*16 + l15; if (qrow > Tq-1) qrow = Tq-1;
        aq[0] = *(const s16x8*)&Qp[(size_t)qrow*64 + l4*8];
        aq[1] = *(const s16x8*)&Qp[(size_t)qrow*64 + 32 + l4*8];
    }
    f32x4 Of[4] = {};
    float m_r[4], l_r[4];
#pragma unroll
    for (int r = 0; r < 4; ++r){ m_r[r] = -INFINITY; l_r[r] = 0.f; }

    int nt = qt + 1;
    int srow = tid >> 2, sq4 = tid & 3;

    uint4 kr0, kr1, vr0, vr1;
    // prologue: issue loads for tile 0
    {
        int krow = 0 + srow; if (krow > Tkv-1) krow = Tkv-1;
        kr0 = *(const uint4*)&Kp[(size_t)krow*64 + sq4*16];
        kr1 = *(const uint4*)&Kp[(size_t)krow*64 + sq4*16 + 8];
        vr0 = *(const uint4*)&Vp[(size_t)srow*vtstride + 0 + sq4*16];
        vr1 = *(const uint4*)&Vp[(size_t)srow*vtstride + 0 + sq4*16 + 8];
    }

    for (int ti = 0; ti < nt; ++ti){
        int ks0 = ti*64;
        // write staged regs -> LDS
        *(uint4*)&Ks[srow][sq4*16]      = kr0;
        *(uint4*)&Ks[srow][sq4*16 + 8]  = kr1;
        *(uint4*)&VTs[srow][sq4*16]     = vr0;
        *(uint4*)&VTs[srow][sq4*16 + 8] = vr1;
        __syncthreads();
        // async-stage split: issue next tile's loads now; they land during compute
        if (ti + 1 < nt){
            int ks1 = ks0 + 64;
            int krow = ks1 + srow; if (krow > Tkv-1) krow = Tkv-1;
            kr0 = *(const uint4*)&Kp[(size_t)krow*64 + sq4*16];
            kr1 = *(const uint4*)&Kp[(size_t)krow*64 + sq4*16 + 8];
            vr0 = *(const uint4*)&Vp[(size_t)srow*vtstride + ks1 + sq4*16];
            vr1 = *(const uint4*)&Vp[(size_t)srow*vtstride + ks1 + sq4*16 + 8];
        }
        // S = Q K^T
        f32x4 sf[4] = {};
#pragma unroll
        for (int kk = 0; kk < 2; ++kk)
#pragma unroll
            for (int ni = 0; ni < 4; ++ni){
                s16x8 bk = *(const s16x8*)&Ks[ni*16 + l15][kk*32 + l4*8];
                sf[ni] = __builtin_amdgcn_mfma_f32_16x16x32_bf16(aq[kk], bk, sf[ni], 0,0,0);
            }
        bool diag = (ti == nt - 1);
        // online softmax (rows: l4*4+r, cols: ni*16+l15)
#pragma unroll
        for (int r = 0; r < 4; ++r){
            int grow = qs + w*16 + l4*4 + r;
            float mx = -INFINITY;
            if (diag){
#pragma unroll
                for (int ni = 0; ni < 4; ++ni){
                    int col = ks0 + ni*16 + l15;
                    float s = sf[ni][r];
                    if (col > grow || col >= Tkv) s = -INFINITY;
                    sf[ni][r] = s;
                    mx = fmaxf(mx, s);
                }
            } else {
#pragma unroll
                for (int ni = 0; ni < 4; ++ni) mx = fmaxf(mx, sf[ni][r]);
            }
            mx = fmaxf(mx, __shfl_xor(mx, 1));
            mx = fmaxf(mx, __shfl_xor(mx, 2));
            mx = fmaxf(mx, __shfl_xor(mx, 4));
            mx = fmaxf(mx, __shfl_xor(mx, 8));
            float mnew = fmaxf(m_r[r], mx);
            float scale = exp2f((m_r[r] - mnew)*LOG2E);
            float rs = 0.f;
#pragma unroll
            for (int ni = 0; ni < 4; ++ni){
                float p = exp2f((sf[ni][r] - mnew)*LOG2E);
                u16 pb = f2b(p);
                rs += b2f(pb);
                Ps[w*16 + l4*4 + r][ni*16 + l15] = pb;
            }
            rs += __shfl_xor(rs, 1);
            rs += __shfl_xor(rs, 2);
            rs += __shfl_xor(rs, 4);
            rs += __shfl_xor(rs, 8);
            l_r[r] = l_r[r]*scale + rs;
            m_r[r] = mnew;
#pragma unroll
            for (int di = 0; di < 4; ++di) Of[di][r] *= scale;
        }
        // no barrier: Ps rows for wave w are written and read by wave w only
        // O += P V
#pragma unroll
        for (int kk = 0; kk < 2; ++kk){
            s16x8 ap = *(const s16x8*)&Ps[w*16 + l15][kk*32 + l4*8];
#pragma unroll
            for (int di = 0; di < 4; ++di){
                s16x8 bv = *(const s16x8*)&VTs[di*16 + l15][kk*32 + l4*8];
                Of[di] = __builtin_amdgcn_mfma_f32_16x16x32_bf16(ap, bv, Of[di], 0,0,0);
            }
        }
        __syncthreads();   // all waves done reading K/V before next overwrite
    }
#pragma unroll
    for (int r = 0; r < 4; ++r){
        int grow = qs + w*16 + l4*4 + r;
        if (grow < Tq){
            float inv = 1.0f / l_r[r];
#pragma unroll
            for (int di = 0; di < 4; ++di)
                O[((size_t)bh*ostride + grow)*64 + di*16 + l15] = Of[di][r] * inv;
        }
    }
}

// ---------------- ysum (B,T,C) bf16 = y1 + shift(y2), vectorized ----------------
__global__ void k_ysum(const float* __restrict__ y1, const float* __restrict__ y2,
                       u16* __restrict__ ys){
    int i = blockIdx.x*blockDim.x + threadIdx.x;
    int stride = gridDim.x*blockDim.x;
    for (; i < (1<<20); i += stride){
        int d4 = i & 15;
        int t = (i >> 4) & 2047;
        int bh = i >> 15;
        float4 s = *(const float4*)&y1[(((size_t)bh*2048) + t)*64 + d4*4];
        if (t > 0){
            float4 z = *(const float4*)&y2[(((size_t)bh*2048) + t - 1)*64 + d4*4];
            s.x += z.x; s.y += z.y; s.z += z.z; s.w += z.w;
        }
        uint2 o;
        o.x = pk2(s.x, s.y);
        o.y = pk2(s.z, s.w);
        int bb = bh >> 4, hh = bh & 15;
        *(uint2*)&ys[(((size_t)bb*2048) + t)*1024 + hh*64 + d4*4] = o;
    }
}

extern "C" void kernel_launch(void* const* d_in, const int* in_sizes, int n_in,
                              void* d_out, int out_size, void* d_ws, size_t ws_size,
                              hipStream_t stream){
    const float* x      = (const float*)d_in[0];
    const float* W_attn = (const float*)d_in[1];
    const float* b_attn = (const float*)d_in[2];
    const float* W_k2   = (const float*)d_in[3];
    const float* b_k2   = (const float*)d_in[4];
    const float* W_proj = (const float*)d_in[5];
    const float* b_proj = (const float*)d_in[6];
    float* out = (float*)d_out;

    char* ws = (char*)d_ws;
    size_t off = 0;
    auto alloc = [&](size_t bytes)->void*{
        void* p = ws + off; off += (bytes + 255) & ~size_t(255); return p;
    };
    u16* xb   = (u16*)alloc((size_t)4096*1024*2);
    u16* WaT  = (u16*)alloc((size_t)2048*1024*2);
    u16* Wk2T = (u16*)alloc((size_t)1024*1024*2);
    u16* WpT  = (u16*)alloc((size_t)1024*1024*2);
    u16* Qb   = (u16*)alloc((size_t)32*2048*64*2);
    u16* Kb   = (u16*)alloc((size_t)32*2048*64*2);
    u16* VTg  = (u16*)alloc((size_t)32*64*2048*2);
    u16* K2b  = (u16*)alloc((size_t)32*2048*64*2);
    u16* ETg  = (u16*)alloc((size_t)32*64*2048*2);
    float* y1 = (float*)alloc((size_t)32*2048*64*4);
    float* y2 = (float*)alloc((size_t)32*2048*64*4);
    u16* ys   = (u16*)alloc((size_t)4096*1024*2);

    k_f32_to_bf16<<<1024, 256, 0, stream>>>(x, xb, 1<<20);
    k_transpose_bf16<<<dim3(64, 32), 256, 0, stream>>>(W_attn, WaT, 1024, 2048);
    k_transpose_bf16<<<dim3(32, 32), 256, 0, stream>>>(W_k2, Wk2T, 1024, 1024);
    k_transpose_bf16<<<dim3(32, 32), 256, 0, stream>>>(W_proj, WpT, 1024, 1024);
    k_build_vT<<<dim3(32, 32), 256, 0, stream>>>(x, VTg);

    k_gemm<0><<<dim3(16, 32), 256, 0, stream>>>(xb, WaT, b_attn, nullptr, Qb, Kb, 4096, 2048, 1024);
    k_gemm<1><<<dim3(8, 32), 256, 0, stream>>>(xb, Wk2T, b_k2, nullptr, K2b, nullptr, 4096, 1024, 1024);

    k_flash<<<dim3(32, 32), 256, 0, stream>>>(Qb, Kb, VTg, y1, 2048, 2048, 2048, 2048, 2048, 2048, 0);
    k_compute_eT<<<dim3(32, 32), 256, 0, stream>>>(x, y1, ETg);
    k_flash<<<dim3(32, 32), 256, 0, stream>>>(Qb, K2b, ETg, y2, 2047, 2047, 2048, 2048, 2048, 2048, 1);
    k_ysum<<<1024, 256, 0, stream>>>(y1, y2, ys);

    k_gemm<2><<<dim3(8, 32), 256, 0, stream>>>(ys, WpT, b_proj, out, nullptr, nullptr, 4096, 1024, 1024);
}

// Round 4
// 355.567 us; speedup vs baseline: 1.3559x; 1.1053x over previous
//
#include <hip/hip_runtime.h>
#include <hip/hip_bf16.h>

typedef unsigned short u16;
typedef short s16x8 __attribute__((ext_vector_type(8)));
typedef float f32x4 __attribute__((ext_vector_type(4)));
typedef float f32x16 __attribute__((ext_vector_type(16)));
typedef unsigned int u32x4 __attribute__((ext_vector_type(4)));

#define LOG2E 1.44269504088896f

__device__ __forceinline__ u16 f2b(float f){
    __hip_bfloat16 h = __float2bfloat16(f);
    return __builtin_bit_cast(unsigned short, h);
}
__device__ __forceinline__ float b2f(u16 u){
    __hip_bfloat16 h = __builtin_bit_cast(__hip_bfloat16, u);
    return __bfloat162float(h);
}
__device__ __forceinline__ unsigned int pk2(float a, float b){
    return (unsigned int)f2b(a) | ((unsigned int)f2b(b) << 16);
}

// ---------------- elementwise fp32 -> bf16 ----------------
__global__ void k_f32_to_bf16(const float* __restrict__ in, u16* __restrict__ out, int n4){
    int i = blockIdx.x*blockDim.x + threadIdx.x;
    int stride = gridDim.x*blockDim.x;
    for (; i < n4; i += stride){
        float4 a = *(const float4*)&in[(size_t)i*4];
        uint2 o;
        o.x = pk2(a.x, a.y);
        o.y = pk2(a.z, a.w);
        *(uint2*)&out[(size_t)i*4] = o;
    }
}

// ---------------- W (KxN fp32) -> Wt (NxK bf16) ----------------
__global__ void k_transpose_bf16(const float* __restrict__ W, u16* __restrict__ Wt, int K, int N){
    __shared__ float tile[32][33];
    int n0 = blockIdx.x*32, k0 = blockIdx.y*32;
    int c = threadIdx.x & 31, r0 = threadIdx.x >> 5;
#pragma unroll
    for (int it = 0; it < 4; ++it){
        int r = r0 + it*8;
        tile[r][c] = W[(size_t)(k0+r)*N + n0 + c];
    }
    __syncthreads();
#pragma unroll
    for (int it = 0; it < 4; ++it){
        int r = r0 + it*8;
        Wt[(size_t)(n0+r)*K + k0 + c] = f2b(tile[c][r]);
    }
}

// ---------------- VT[(b,h,d,t)] = bf16(x[b,t,h*64+d]) ----------------
__global__ __launch_bounds__(256) void k_build_vT(const float* __restrict__ x, u16* __restrict__ VT){
    __shared__ float tile[64][65];
    int bh = blockIdx.x, t0 = blockIdx.y*64;
    int b = bh >> 4, h = bh & 15;
    int tid = threadIdx.x;
    {
        int tt = tid >> 2, ds = (tid & 3)*16;
        const float* xp = &x[((size_t)(b*2048) + t0 + tt)*1024 + h*64 + ds];
#pragma unroll
        for (int j4 = 0; j4 < 4; ++j4){
            float4 a = *(const float4*)&xp[j4*4];
            tile[tt][ds + j4*4 + 0] = a.x;
            tile[tt][ds + j4*4 + 1] = a.y;
            tile[tt][ds + j4*4 + 2] = a.z;
            tile[tt][ds + j4*4 + 3] = a.w;
        }
    }
    __syncthreads();
    {
        int dd = tid >> 2, ts = (tid & 3)*16;
        unsigned int o[8];
#pragma unroll
        for (int j = 0; j < 8; ++j)
            o[j] = pk2(tile[ts + 2*j][dd], tile[ts + 2*j + 1][dd]);
        u16* dst = &VT[((size_t)(bh*64 + dd))*2048 + t0 + ts];
        *(uint4*)&dst[0] = *(uint4*)&o[0];
        *(uint4*)&dst[8] = *(uint4*)&o[4];
    }
}

// ---------------- ET[(bh,d,j)] = bf16(x[b,j+1,h*64+d] - y1T[bh,d,j]); j==2047 -> 0 ----------------
__global__ __launch_bounds__(256) void k_compute_eT(const float* __restrict__ x, const float* __restrict__ y1T,
                                                    u16* __restrict__ ET){
    __shared__ float tile[64][65];
    int bh = blockIdx.x, j0 = blockIdx.y*64;
    int b = bh >> 4, h = bh & 15;
    int tid = threadIdx.x;
    {
        int tt = tid >> 2, ds = (tid & 3)*16;
        int j = j0 + tt;
        int xr = (j <= 2046) ? (j + 1) : 2047;   // clamp; col 2047 zeroed at write
        const float* xp = &x[((size_t)(b*2048) + xr)*1024 + h*64 + ds];
#pragma unroll
        for (int j4 = 0; j4 < 4; ++j4){
            float4 a = *(const float4*)&xp[j4*4];
            tile[tt][ds + j4*4 + 0] = a.x;
            tile[tt][ds + j4*4 + 1] = a.y;
            tile[tt][ds + j4*4 + 2] = a.z;
            tile[tt][ds + j4*4 + 3] = a.w;
        }
    }
    __syncthreads();
    {
        int dd = tid >> 2, ts = (tid & 3)*16;
        const float* yp = &y1T[((size_t)(bh*64 + dd))*2048 + j0 + ts];
        unsigned int o[8];
#pragma unroll
        for (int j = 0; j < 8; ++j){
            int c0 = ts + 2*j, c1 = ts + 2*j + 1;
            float e0 = (j0 + c0 <= 2046) ? (tile[c0][dd] - yp[2*j])   : 0.f;
            float e1 = (j0 + c1 <= 2046) ? (tile[c1][dd] - yp[2*j+1]) : 0.f;
            o[j] = pk2(e0, e1);
        }
        u16* dst = &ET[((size_t)(bh*64 + dd))*2048 + j0 + ts];
        *(uint4*)&dst[0] = *(uint4*)&o[0];
        *(uint4*)&dst[8] = *(uint4*)&o[4];
    }
}

// ---------------- bf16 MFMA GEMM, 128x128 tile, BK=64 ----------------
template<int MODE>
__global__ __launch_bounds__(256) void k_gemm(const u16* __restrict__ A, const u16* __restrict__ Bt,
                       const float* __restrict__ bias, float* __restrict__ outF,
                       u16* __restrict__ out0, u16* __restrict__ out1,
                       int M, int N, int K){
    __shared__ u16 As[128][72];
    __shared__ u16 Bs[128][72];
    int m0 = blockIdx.y * 128, n0 = blockIdx.x * 128;
    int tid = threadIdx.x;
    int lane = tid & 63, w = tid >> 6;
    int wm = w >> 1, wn = w & 1;
    int l15 = lane & 15, l4 = lane >> 4;
    f32x4 acc[4][4] = {};

    for (int kt = 0; kt < K; kt += 64){
#pragma unroll
        for (int it = 0; it < 4; ++it){
            int c = tid + 256*it;
            int row = c >> 3, seg = c & 7;
            *(uint4*)&As[row][seg*8] = *(const uint4*)&A[(size_t)(m0+row)*K + kt + seg*8];
            *(uint4*)&Bs[row][seg*8] = *(const uint4*)&Bt[(size_t)(n0+row)*K + kt + seg*8];
        }
        __syncthreads();
#pragma unroll
        for (int kk = 0; kk < 2; ++kk){
            s16x8 a[4], b[4];
#pragma unroll
            for (int mi = 0; mi < 4; ++mi)
                a[mi] = *(const s16x8*)&As[wm*64 + mi*16 + l15][kk*32 + l4*8];
#pragma unroll
            for (int ni = 0; ni < 4; ++ni)
                b[ni] = *(const s16x8*)&Bs[wn*64 + ni*16 + l15][kk*32 + l4*8];
#pragma unroll
            for (int mi = 0; mi < 4; ++mi)
#pragma unroll
                for (int ni = 0; ni < 4; ++ni)
                    acc[mi][ni] = __builtin_amdgcn_mfma_f32_16x16x32_bf16(a[mi], b[ni], acc[mi][ni], 0,0,0);
        }
        __syncthreads();
    }

#pragma unroll
    for (int mi = 0; mi < 4; ++mi){
        int growb = m0 + wm*64 + mi*16 + l4*4;
#pragma unroll
        for (int ni = 0; ni < 4; ++ni){
            int gcol = n0 + wn*64 + ni*16 + l15;
            float bv = bias[gcol];
#pragma unroll
            for (int r = 0; r < 4; ++r){
                int row = growb + r;
                float val = acc[mi][ni][r];
                if (MODE == 2){
                    outF[(size_t)row*N + gcol] = val + 2.0f*bv;
                } else {
                    val += bv;
                    int bb = row >> 11, t = row & 2047;
                    if (MODE == 0){
                        if (gcol < 1024){
                            int h = gcol >> 6, dd = gcol & 63;
                            out0[(((size_t)(bb*16+h))*2048 + t)*64 + dd] = f2b(val*0.125f);
                        } else {
                            int c2 = gcol - 1024;
                            int h = c2 >> 6, dd = c2 & 63;
                            out1[(((size_t)(bb*16+h))*2048 + t)*64 + dd] = f2b(val);
                        }
                    } else {
                        int h = gcol >> 6, dd = gcol & 63;
                        out0[(((size_t)(bb*16+h))*2048 + t)*64 + dd] = f2b(val);
                    }
                }
            }
        }
    }
}

// ---------------- flash attention, 32x32 swapped-operand structure ----------------
// Q,K bf16 rows (bh, t, 64); VT bf16 (bh, d=64, t=2048). Output OT fp32 (bh, d=64, t=2048).
// Block: 4 waves x 32 q-rows (QBLK=128). Pair-balanced causal grid: (bh=32, pair=8);
// block processes qtile `pair` then `15-pair` -> exactly 34 kv-tile-steps per block.
__global__ __launch_bounds__(256) void k_flash32(const u16* __restrict__ Q, const u16* __restrict__ Km,
                         const u16* __restrict__ VT, float* __restrict__ OT,
                         int Tq, int Tkv, int qoff){
    __shared__ u16 Ks[64*64];
    __shared__ u16 Vs[64*64];
    int bh = blockIdx.x;
    int pair = blockIdx.y;
    int tid = threadIdx.x;
    int lane = tid & 63, w = tid >> 6;
    int l31 = lane & 31, hi = lane >> 5;
    const u16* Qp = Q + ((size_t)bh*2048 + qoff)*64;
    const u16* Kp = Km + (size_t)bh*2048*64;
    const u16* Vp = VT + (size_t)bh*64*2048;
    float* Op = OT + (size_t)bh*64*2048;

    int srow = tid >> 2;        // staging row 0..63
    int sc   = tid & 3;         // staging chunk -> 16B slots 2sc, 2sc+1

#pragma unroll 1
    for (int half = 0; half < 2; ++half){
        int t = half ? (15 - pair) : pair;
        int ntile = 2*t + 2;
        int q0w = t*128 + w*32;
        int qi = q0w + l31; if (qi > Tq-1) qi = Tq-1;

        // Q fragments in registers (B-operand of swapped QK^T)
        s16x8 qf[4];
#pragma unroll
        for (int st = 0; st < 4; ++st)
            qf[st] = *(const s16x8*)&Qp[(size_t)qi*64 + st*16 + hi*8];

        f32x16 accO[2] = {};
        float m_r = -INFINITY, l_r = 0.f;

        uint4 kr0, kr1, vr0, vr1;
        {   // prologue: tile 0
            int kvr = srow; if (kvr > Tkv-1) kvr = Tkv-1;
            kr0 = *(const uint4*)&Kp[(size_t)kvr*64 + sc*16];
            kr1 = *(const uint4*)&Kp[(size_t)kvr*64 + sc*16 + 8];
            vr0 = *(const uint4*)&Vp[(size_t)srow*2048 + sc*16];
            vr1 = *(const uint4*)&Vp[(size_t)srow*2048 + sc*16 + 8];
        }

        for (int i = 0; i < ntile; ++i){
            int kv0 = i*64;
            {   // staged regs -> LDS, XOR-swizzled 16B slots
                int sw = srow & 7;
                *(uint4*)&Ks[srow*64 + (((2*sc)   ^ sw)*8)] = kr0;
                *(uint4*)&Ks[srow*64 + (((2*sc+1) ^ sw)*8)] = kr1;
                *(uint4*)&Vs[srow*64 + (((2*sc)   ^ sw)*8)] = vr0;
                *(uint4*)&Vs[srow*64 + (((2*sc+1) ^ sw)*8)] = vr1;
            }
            __syncthreads();
            if (i + 1 < ntile){   // async-stage next tile
                int kv1 = kv0 + 64;
                int kvr = kv1 + srow; if (kvr > Tkv-1) kvr = Tkv-1;
                kr0 = *(const uint4*)&Kp[(size_t)kvr*64 + sc*16];
                kr1 = *(const uint4*)&Kp[(size_t)kvr*64 + sc*16 + 8];
                vr0 = *(const uint4*)&Vp[(size_t)srow*2048 + kv1 + sc*16];
                vr1 = *(const uint4*)&Vp[(size_t)srow*2048 + kv1 + sc*16 + 8];
            }
            if (kv0 <= q0w + 31){
                // S^T = K x Q : lane owns q = l31, k rows in-register
                f32x16 accS[2] = {};
#pragma unroll
                for (int m = 0; m < 2; ++m){
                    int row = 32*m + l31;
                    int sw = row & 7;
#pragma unroll
                    for (int st = 0; st < 4; ++st){
                        s16x8 a = *(const s16x8*)&Ks[row*64 + (((2*st + hi) ^ sw)*8)];
                        accS[m] = __builtin_amdgcn_mfma_f32_32x32x16_bf16(a, qf[st], accS[m], 0,0,0);
                    }
                }
                float p[32];
                bool diag = (kv0 + 63 > q0w);
#pragma unroll
                for (int m = 0; m < 2; ++m)
#pragma unroll
                    for (int r = 0; r < 16; ++r){
                        float s = accS[m][r];
                        if (diag){
                            int kg = kv0 + 32*m + (r&3) + 8*(r>>2) + 4*hi;
                            if (kg > qi) s = -INFINITY;
                        }
                        p[m*16 + r] = s;
                    }
                // in-lane max (31 fmax) + 1 cross-half swap
                float mx = p[0];
#pragma unroll
                for (int j = 1; j < 32; ++j) mx = fmaxf(mx, p[j]);
                mx = fmaxf(mx, __shfl_xor(mx, 32));
                float mnew = fmaxf(m_r, mx);
                if (!__all(mx - m_r <= 8.f)){   // defer-max (T13)
                    float scl = exp2f((m_r - mnew)*LOG2E);
#pragma unroll
                    for (int dt = 0; dt < 2; ++dt)
#pragma unroll
                        for (int r = 0; r < 16; ++r) accO[dt][r] *= scl;
                    l_r *= scl;
                    m_r = mnew;
                }
                float rs = 0.f;
#pragma unroll
                for (int j = 0; j < 32; ++j){
                    p[j] = exp2f((p[j] - m_r)*LOG2E);
                    rs += p[j];
                }
                rs += __shfl_xor(rs, 32);
                l_r += rs;
                // PV as O^T = V^T x P^T ; P-frag via cvt_pk + shfl_xor(32)
#pragma unroll
                for (int m = 0; m < 2; ++m)
#pragma unroll
                    for (int s2 = 0; s2 < 2; ++s2){
                        const float* pp = &p[m*16 + s2*8];
                        unsigned dwa = pk2(pp[0], pp[1]);
                        unsigned dwb = pk2(pp[2], pp[3]);
                        unsigned dwc = pk2(pp[4], pp[5]);
                        unsigned dwd = pk2(pp[6], pp[7]);
                        unsigned xa = (unsigned)__shfl_xor((int)dwa, 32);
                        unsigned xb = (unsigned)__shfl_xor((int)dwb, 32);
                        unsigned xc = (unsigned)__shfl_xor((int)dwc, 32);
                        unsigned xd = (unsigned)__shfl_xor((int)dwd, 32);
                        u32x4 fv;
                        fv.x = hi ? xc : dwa;
                        fv.y = hi ? xd : dwb;
                        fv.z = hi ? dwc : xa;
                        fv.w = hi ? dwd : xb;
                        s16x8 pf = __builtin_bit_cast(s16x8, fv);
                        int vslot = m*4 + s2*2 + hi;
#pragma unroll
                        for (int dt = 0; dt < 2; ++dt){
                            int vrow = dt*32 + l31;
                            s16x8 va = *(const s16x8*)&Vs[vrow*64 + ((vslot ^ (vrow&7))*8)];
                            accO[dt] = __builtin_amdgcn_mfma_f32_32x32x16_bf16(va, pf, accO[dt], 0,0,0);
                        }
                    }
            }
            __syncthreads();
        }
        // write O^T (bh, d, t); lane q = qi
        float inv = 1.0f / l_r;
#pragma unroll
        for (int dt = 0; dt < 2; ++dt)
#pragma unroll
            for (int r = 0; r < 16; ++r){
                int d = dt*32 + (r&3) + 8*(r>>2) + 4*hi;
                Op[(size_t)d*2048 + qi] = accO[dt][r] * inv;
            }
        __syncthreads();   // protect LDS before next half's staging
    }
}

// ---------------- ys (B,T,C) bf16 = y1T + shift(y2T), transposing ----------------
__global__ __launch_bounds__(256) void k_ysum(const float* __restrict__ y1T, const float* __restrict__ y2T,
                                              u16* __restrict__ ys){
    __shared__ float tile[64][65];
    int bh = blockIdx.x, t0 = blockIdx.y*64;
    int b = bh >> 4, h = bh & 15;
    int tid = threadIdx.x;
    {
        int dd = tid >> 2, ts = (tid & 3)*16;
        const float* y1p = &y1T[((size_t)(bh*64 + dd))*2048 + t0 + ts];
        const float* y2p = &y2T[((size_t)(bh*64 + dd))*2048 + t0 + ts - 1];
#pragma unroll
        for (int c = 0; c < 16; ++c){
            int tg = t0 + ts + c;
            float s = y1p[c];
            if (tg > 0) s += y2p[c];
            tile[ts + c][dd] = s;
        }
    }
    __syncthreads();
    {
        int tt = tid >> 2, ds = (tid & 3)*16;
        unsigned int o[8];
#pragma unroll
        for (int j = 0; j < 8; ++j)
            o[j] = pk2(tile[tt][ds + 2*j], tile[tt][ds + 2*j + 1]);
        u16* dst = &ys[((size_t)(b*2048) + t0 + tt)*1024 + h*64 + ds];
        *(uint4*)&dst[0] = *(uint4*)&o[0];
        *(uint4*)&dst[8] = *(uint4*)&o[4];
    }
}

extern "C" void kernel_launch(void* const* d_in, const int* in_sizes, int n_in,
                              void* d_out, int out_size, void* d_ws, size_t ws_size,
                              hipStream_t stream){
    const float* x      = (const float*)d_in[0];
    const float* W_attn = (const float*)d_in[1];
    const float* b_attn = (const float*)d_in[2];
    const float* W_k2   = (const float*)d_in[3];
    const float* b_k2   = (const float*)d_in[4];
    const float* W_proj = (const float*)d_in[5];
    const float* b_proj = (const float*)d_in[6];
    float* out = (float*)d_out;

    char* ws = (char*)d_ws;
    size_t off = 0;
    auto alloc = [&](size_t bytes)->void*{
        void* p = ws + off; off += (bytes + 255) & ~size_t(255); return p;
    };
    u16* xb    = (u16*)alloc((size_t)4096*1024*2);
    u16* WaT   = (u16*)alloc((size_t)2048*1024*2);
    u16* Wk2T  = (u16*)alloc((size_t)1024*1024*2);
    u16* WpT   = (u16*)alloc((size_t)1024*1024*2);
    u16* Qb    = (u16*)alloc((size_t)32*2048*64*2);
    u16* Kb    = (u16*)alloc((size_t)32*2048*64*2);
    u16* VTg   = (u16*)alloc((size_t)32*64*2048*2);
    u16* K2b   = (u16*)alloc((size_t)32*2048*64*2);
    u16* ETg   = (u16*)alloc((size_t)32*64*2048*2);
    float* y1T = (float*)alloc((size_t)32*64*2048*4);
    float* y2T = (float*)alloc((size_t)32*64*2048*4);
    u16* ys    = (u16*)alloc((size_t)4096*1024*2);

    k_f32_to_bf16<<<1024, 256, 0, stream>>>(x, xb, 1<<20);
    k_transpose_bf16<<<dim3(64, 32), 256, 0, stream>>>(W_attn, WaT, 1024, 2048);
    k_transpose_bf16<<<dim3(32, 32), 256, 0, stream>>>(W_k2, Wk2T, 1024, 1024);
    k_transpose_bf16<<<dim3(32, 32), 256, 0, stream>>>(W_proj, WpT, 1024, 1024);
    k_build_vT<<<dim3(32, 32), 256, 0, stream>>>(x, VTg);

    k_gemm<0><<<dim3(16, 32), 256, 0, stream>>>(xb, WaT, b_attn, nullptr, Qb, Kb, 4096, 2048, 1024);
    k_gemm<1><<<dim3(8, 32), 256, 0, stream>>>(xb, Wk2T, b_k2, nullptr, K2b, nullptr, 4096, 1024, 1024);

    k_flash32<<<dim3(32, 8), 256, 0, stream>>>(Qb, Kb, VTg, y1T, 2048, 2048, 0);
    k_compute_eT<<<dim3(32, 32), 256, 0, stream>>>(x, y1T, ETg);
    k_flash32<<<dim3(32, 8), 256, 0, stream>>>(Qb, K2b, ETg, y2T, 2047, 2047, 1);
    k_ysum<<<dim3(32, 32), 256, 0, stream>>>(y1T, y2T, ys);

    k_gemm<2><<<dim3(8, 32), 256, 0, stream>>>(ys, WpT, b_proj, out, nullptr, nullptr, 4096, 1024, 1024);
}